// Round 8
// baseline (984.469 us; speedup 1.0000x reference)
//
#include <hip/hip_runtime.h>
#include <cmath>

#define M_ROWS  65536
#define D_DIM   64
#define K_CODES 4096

// d_out float offsets (z_q_st | indices | vq_loss | perplexity | z_q)
#define OFF_IDX  4194304
#define OFF_SCAL 4259840
#define OFF_ZQ   4259842

// scratch regions inside d_out (consumed before their region is written)
#define IMG_OFF   (4u << 20)                 // codebook image, 1 MB (in z_q_st region)
#define E2B_OFF   (IMG_OFF + 1048576u)       // e2+32 array, 16 KB
#define CANDB_OFF 17039368u                  // == OFF_ZQ*4 : fallback cand64 region (16 MB, overwritten by copy_zq)

// codebook chunk image: 128 codes, bf16 hi/lo split, 128 B/row, XOR-swizzled granules
#define CH_LO    16384
#define CH_BYTES 32768
#define CH_QUADS 2048
#define NSPLIT   8
#define NCHB     4                            // chunks per block (512 codes)

typedef __attribute__((ext_vector_type(8))) short s16x8;
typedef __attribute__((ext_vector_type(4))) float f32x4;
typedef unsigned long long u64;

__device__ __forceinline__ unsigned short f2bf(float f) {   // RNE float->bf16 bits
  unsigned int u = __float_as_uint(f);
  return (unsigned short)((u + 0x7FFFu + ((u >> 16) & 1u)) >> 16);
}
__device__ __forceinline__ float bf2f(unsigned short h) {
  return __uint_as_float(((unsigned int)h) << 16);
}
__device__ __forceinline__ unsigned int umin_(unsigned int a, unsigned int b) {
  return a < b ? a : b;
}
// second-min update: with invariant b1 <= b2, new b2 = median(old b1, b2, key)
__device__ __forceinline__ unsigned int med3_u32(unsigned int a, unsigned int b, unsigned int c) {
  unsigned int d;
  asm("v_med3_u32 %0, %1, %2, %3" : "=v"(d) : "v"(a), "v"(b), "v"(c));
  return d;
}

// ---------------------------------------------------------------------------
// K1a: e2[k] exact (numpy 8-accumulator pairwise pattern, float4 loads)
// ---------------------------------------------------------------------------
__global__ void e2_kernel(const float* __restrict__ cb,
                          float* __restrict__ e2, float* __restrict__ e2b) {
  int k = blockIdx.x * 256 + threadIdx.x;
  if (k >= K_CODES) return;
  const float4* row = (const float4*)(cb + (size_t)k * D_DIM);
  float4 q[16];
#pragma unroll
  for (int i = 0; i < 16; ++i) q[i] = row[i];
  float s;
  {
#pragma clang fp contract(off)
    float r[8];
    {
      const float* f = (const float*)&q[0];
#pragma unroll
      for (int j = 0; j < 8; ++j) r[j] = f[j] * f[j];
    }
#pragma unroll
    for (int a = 1; a < 8; ++a) {
      const float* f = (const float*)&q[2 * a];
#pragma unroll
      for (int j = 0; j < 8; ++j) r[j] = r[j] + f[j] * f[j];
    }
    s = ((r[0] + r[1]) + (r[2] + r[3])) + ((r[4] + r[5]) + (r[6] + r[7]));
  }
  e2[k] = s;
  e2b[k] = s + 32.0f;
}

// ---------------------------------------------------------------------------
// K1b: bf16 hi/lo split image, fully coalesced; granule g at ((g+r)&7)
// ---------------------------------------------------------------------------
__global__ void img_kernel(const float* __restrict__ cb, char* __restrict__ img) {
  int t = blockIdx.x * 256 + threadIdx.x;   // 65536 threads, 4 elements each
  int k  = t >> 4;
  int d0 = (t & 15) * 4;
  float4 f = ((const float4*)cb)[t];
  ushort4 hi, lo;
  hi.x = f2bf(f.x); lo.x = f2bf(f.x - bf2f(hi.x));
  hi.y = f2bf(f.y); lo.y = f2bf(f.y - bf2f(hi.y));
  hi.z = f2bf(f.z); lo.z = f2bf(f.z - bf2f(hi.z));
  hi.w = f2bf(f.w); lo.w = f2bf(f.w - bf2f(hi.w));
  int c = k >> 7, r = k & 127;
  int g = d0 >> 3;
  int off = ((g + r) & 7) * 16 + (d0 & 7) * 2;
  char* base = img + (size_t)c * CH_BYTES + r * 128;
  *(ushort4*)(base + off) = hi;
  *(ushort4*)(base + CH_LO + off) = lo;
}

// ---------------------------------------------------------------------------
// K2: MFMA distance pass. 512 threads = 8 waves x 64 rows = 512 rows/block;
// K-split 8 -> grid 1024 = 4 blocks/CU (occupancy cap 100% vs round-6's 50%).
// val = (e2+32) - 2 z.e via 3 bf16-split products, e2 as read-only MFMA C.
// key = (bits&~0xFF)|tile (tile = sp*32+c*8+t, 8 bits); top-2/elem via
// min+med3; per-row top-4-of-32 keys -> cand64[row*32+sp*4+i] = key<<32 | k.
// ---------------------------------------------------------------------------
__global__ __launch_bounds__(512, 8)
void vq_mfma_kernel(const float* __restrict__ z_e,
                    const char* __restrict__ img,
                    const float* __restrict__ e2b,
                    u64* __restrict__ cand64) {
  __shared__ union {
    uint4 q[CH_QUADS];
    char raw[CH_BYTES];
    unsigned int cand[256 * 33];     // 33792 B
  } sm;
  __shared__ float lds_e2[128];
  const int tid  = threadIdx.x;
  const int wave = tid >> 6, lane = tid & 63;
  const int quad = lane >> 4, c16 = lane & 15;
  const int rb   = blockIdx.x >> 3;           // row-group of 512
  const int sp   = blockIdx.x & 7;            // K-split id
  const int mb   = rb * 512 + wave * 64;

  // A-fragments: 4 row-tiles x (k-halves) x (hi/lo), A[m=lane&15][k=quad*8+j]
  s16x8 zh[4][2], zl[4][2];
#pragma unroll
  for (int mt = 0; mt < 4; ++mt) {
    int m = mb + mt * 16 + c16;
#pragma unroll
    for (int s = 0; s < 2; ++s) {
      const float* zp = z_e + (size_t)m * 64 + s * 32 + quad * 8;
      float4 fa = ((const float4*)zp)[0];
      float4 fb = ((const float4*)zp)[1];
      float v[8] = {fa.x, fa.y, fa.z, fa.w, fb.x, fb.y, fb.z, fb.w};
      union { s16x8 v8; unsigned short e[8]; } H, L;
#pragma unroll
      for (int j = 0; j < 8; ++j) {
        float f = -2.0f * v[j];
        unsigned short h = f2bf(f);
        H.e[j] = h;
        L.e[j] = f2bf(f - bf2f(h));
      }
      zh[mt][s] = H.v8;
      zl[mt][s] = L.v8;
    }
  }

  unsigned int b1[4][4], b2[4][4];
#pragma unroll
  for (int mt = 0; mt < 4; ++mt)
#pragma unroll
    for (int r = 0; r < 4; ++r) { b1[mt][r] = 0xFFFFFFFFu; b2[mt][r] = 0xFFFFFFFFu; }

  const int swz0 = ((quad + c16) & 7) * 16;       // t-invariant swizzle offsets
  const int swz1 = ((quad + 4 + c16) & 7) * 16;

  for (int c = 0; c < NCHB; ++c) {
    __syncthreads();
    {
      const uint4* src = (const uint4*)(img + (size_t)(sp * NCHB + c) * CH_BYTES);
#pragma unroll
      for (int i = 0; i < 4; ++i) sm.q[tid + i * 512] = src[tid + i * 512];
      if (tid < 128) lds_e2[tid] = e2b[sp * 512 + c * 128 + tid];
    }
    __syncthreads();

#pragma unroll 1
    for (int t = 0; t < 8; ++t) {
      const char* hb = sm.raw + (t * 16 + c16) * 128;
      s16x8 Bh0 = *(const s16x8*)(hb + swz0);
      s16x8 Bh1 = *(const s16x8*)(hb + swz1);
      s16x8 Bl0 = *(const s16x8*)(hb + CH_LO + swz0);
      s16x8 Bl1 = *(const s16x8*)(hb + CH_LO + swz1);
      float e2v = lds_e2[t * 16 + c16];
      unsigned int tid8 = (unsigned int)(sp * 32 + c * 8 + t);  // global 16-code tile id
      f32x4 cvec = {e2v, e2v, e2v, e2v};

#pragma unroll
      for (int mt = 0; mt < 4; ++mt) {
        f32x4 acc;
        acc = __builtin_amdgcn_mfma_f32_16x16x32_bf16(zh[mt][0], Bh0, cvec, 0, 0, 0);
        acc = __builtin_amdgcn_mfma_f32_16x16x32_bf16(zh[mt][1], Bh1, acc, 0, 0, 0);
        acc = __builtin_amdgcn_mfma_f32_16x16x32_bf16(zl[mt][0], Bh0, acc, 0, 0, 0);
        acc = __builtin_amdgcn_mfma_f32_16x16x32_bf16(zl[mt][1], Bh1, acc, 0, 0, 0);
        acc = __builtin_amdgcn_mfma_f32_16x16x32_bf16(zh[mt][0], Bl0, acc, 0, 0, 0);
        acc = __builtin_amdgcn_mfma_f32_16x16x32_bf16(zh[mt][1], Bl1, acc, 0, 0, 0);
#pragma unroll
        for (int r = 0; r < 4; ++r) {
          unsigned int key = (__float_as_uint(acc[r]) & 0xFFFFFF00u) | tid8;
          b2[mt][r] = med3_u32(b1[mt][r], b2[mt][r], key);
          b1[mt][r] = umin_(b1[mt][r], key);
        }
      }
    }
  }

  // final selection: two passes of 256 rows through the cand buffer
  for (int pass = 0; pass < 2; ++pass) {
    __syncthreads();
    if ((wave >> 2) == pass) {
      int wl = wave & 3;
#pragma unroll
      for (int mt = 0; mt < 4; ++mt)
#pragma unroll
        for (int r = 0; r < 4; ++r) {
          int lr = wl * 64 + mt * 16 + quad * 4 + r;   // C: col=lane&15, row=quad*4+reg
          sm.cand[lr * 33 + c16 * 2 + 0] = b1[mt][r];
          sm.cand[lr * 33 + c16 * 2 + 1] = b2[mt][r];
        }
    }
    __syncthreads();
    if (tid < 256) {
      unsigned int kk[4] = {0xFFFFFFFFu, 0xFFFFFFFFu, 0xFFFFFFFFu, 0xFFFFFFFFu};
      unsigned int vv[4] = {0, 0, 0, 0};
      for (int j = 0; j < 32; ++j) {
        unsigned int key = sm.cand[tid * 33 + j];
        if (key < kk[3]) {
          kk[3] = key;
          vv[3] = (key & 0xFFu) * 16 + (unsigned int)(j >> 1);  // k = tile*16 + col
          for (int p = 3; p > 0; --p)
            if (kk[p] < kk[p - 1]) {
              unsigned int a = kk[p]; kk[p] = kk[p - 1]; kk[p - 1] = a;
              unsigned int b = vv[p]; vv[p] = vv[p - 1]; vv[p - 1] = b;
            }
        }
      }
      int grow = rb * 512 + pass * 256 + tid;
#pragma unroll
      for (int i = 0; i < 4; ++i)
        cand64[(size_t)grow * 32 + sp * 4 + i] = ((u64)kk[i] << 32) | (u64)vv[i];
    }
  }
}

// ---------------------------------------------------------------------------
// K3: tail. ONE THREAD PER ROW, all 64 lanes busy, no barrier/LDS/atomics.
// Merge 32 cand64 -> top-6 by key (u64 compare; key quantum 0.002 >> 1e-5
// approx error; >=6 near-ties of the global min required for a miss),
// exact-check 6 with the bit-exact numpy formula, first-min tie-break.
// Writes idx + z_q_st (+ z_q if flag) + per-wave loss partials.
// ---------------------------------------------------------------------------
__global__ __launch_bounds__(128)
void pick_kernel(const float* __restrict__ z_e, const float* __restrict__ cb,
                 const float* __restrict__ e2, const u64* __restrict__ cand64,
                 float* __restrict__ out, double* __restrict__ partials, int write_zq) {
  const int tid = threadIdx.x;
  const int r   = blockIdx.x * 128 + tid;

  // top-6 of 32 by u64 (key in high bits; low bits = k, so equal keys prefer smaller k)
  u64 t6[6] = {~0ull, ~0ull, ~0ull, ~0ull, ~0ull, ~0ull};
  {
    const u64* cp = cand64 + (size_t)r * 32;
#pragma unroll 1
    for (int j = 0; j < 32; ++j) {
      u64 v = cp[j];
      if (v < t6[5]) {
        t6[5] = v;
#pragma unroll
        for (int p = 5; p > 0; --p)
          if (t6[p] < t6[p - 1]) { u64 a = t6[p]; t6[p] = t6[p - 1]; t6[p - 1] = a; }
      }
    }
  }

  // z row + exact z2 (numpy 8-accumulator pairwise pattern)
  const float4* zr = (const float4*)(z_e + (size_t)r * 64);
  float4 z4[16];
#pragma unroll
  for (int i = 0; i < 16; ++i) z4[i] = zr[i];
  float z2;
  {
#pragma clang fp contract(off)
    float rr[8];
    {
      const float* f = (const float*)&z4[0];
#pragma unroll
      for (int j = 0; j < 8; ++j) rr[j] = f[j] * f[j];
    }
#pragma unroll
    for (int a = 1; a < 8; ++a) {
      const float* f = (const float*)&z4[2 * a];
#pragma unroll
      for (int j = 0; j < 8; ++j) rr[j] = rr[j] + f[j] * f[j];
    }
    z2 = ((rr[0] + rr[1]) + (rr[2] + rr[3])) + ((rr[4] + rr[5]) + (rr[6] + rr[7]));
  }

  float bd = INFINITY;
  int bk = K_CODES;
#pragma unroll 1
  for (int i = 0; i < 6; ++i) {
    int k = (int)(unsigned int)(t6[i] & 0xFFFFu);
    const float4* ev = (const float4*)(cb + (size_t)k * 64);
    float4 a0 = make_float4(0.f, 0.f, 0.f, 0.f);
    float4 a1 = make_float4(0.f, 0.f, 0.f, 0.f);
    float4 a2 = make_float4(0.f, 0.f, 0.f, 0.f);
    float4 a3 = make_float4(0.f, 0.f, 0.f, 0.f);
#pragma unroll
    for (int q = 0; q < 4; ++q) {
      float4 e0 = ev[4 * q + 0], e1 = ev[4 * q + 1], e2v = ev[4 * q + 2], e3 = ev[4 * q + 3];
      a0.x = fmaf(z4[4 * q + 0].x, e0.x, a0.x); a0.y = fmaf(z4[4 * q + 0].y, e0.y, a0.y);
      a0.z = fmaf(z4[4 * q + 0].z, e0.z, a0.z); a0.w = fmaf(z4[4 * q + 0].w, e0.w, a0.w);
      a1.x = fmaf(z4[4 * q + 1].x, e1.x, a1.x); a1.y = fmaf(z4[4 * q + 1].y, e1.y, a1.y);
      a1.z = fmaf(z4[4 * q + 1].z, e1.z, a1.z); a1.w = fmaf(z4[4 * q + 1].w, e1.w, a1.w);
      a2.x = fmaf(z4[4 * q + 2].x, e2v.x, a2.x); a2.y = fmaf(z4[4 * q + 2].y, e2v.y, a2.y);
      a2.z = fmaf(z4[4 * q + 2].z, e2v.z, a2.z); a2.w = fmaf(z4[4 * q + 2].w, e2v.w, a2.w);
      a3.x = fmaf(z4[4 * q + 3].x, e3.x, a3.x); a3.y = fmaf(z4[4 * q + 3].y, e3.y, a3.y);
      a3.z = fmaf(z4[4 * q + 3].z, e3.z, a3.z); a3.w = fmaf(z4[4 * q + 3].w, e3.w, a3.w);
    }
    float d;
    {
#pragma clang fp contract(off)
      float sx = (a0.x + a1.x) + (a2.x + a3.x);
      float sy = (a0.y + a1.y) + (a2.y + a3.y);
      float sz = (a0.z + a1.z) + (a2.z + a3.z);
      float sw = (a0.w + a1.w) + (a2.w + a3.w);
      float dot = (sx + sy) + (sz + sw);
      float tt = z2 + e2[k];
      d = tt - 2.0f * dot;
    }
    if (d < bd || (d == bd && k < bk)) { bd = d; bk = k; }
  }

  out[OFF_IDX + r] = (float)bk;

  // winner row: re-gather (L1-hot), write outputs, commit-loss partial
  const float4* qv = (const float4*)(cb + (size_t)bk * 64);
  float4* o0 = (float4*)(out + (size_t)r * 64);
  float* o1 = out + OFF_ZQ + (size_t)r * 64;     // 8B-aligned only
  double csum = 0.0;
#pragma unroll
  for (int i = 0; i < 16; ++i) {
    float4 q = qv[i];
    o0[i] = q;
    if (write_zq) {
      ((float2*)o1)[2 * i]     = make_float2(q.x, q.y);
      ((float2*)o1)[2 * i + 1] = make_float2(q.z, q.w);
    }
    float dx = z4[i].x - q.x; csum += (double)dx * (double)dx;
    float dy = z4[i].y - q.y; csum += (double)dy * (double)dy;
    float dz = z4[i].z - q.z; csum += (double)dz * (double)dz;
    float dw = z4[i].w - q.w; csum += (double)dw * (double)dw;
  }
#pragma unroll
  for (int off = 32; off > 0; off >>= 1) csum += __shfl_down(csum, off);
  if ((tid & 63) == 0) partials[blockIdx.x * 2 + (tid >> 6)] = csum;
}

// ---------------------------------------------------------------------------
// K4 (fallback only): z_q <- z_q_st; overwrites cand scratch in z_q region.
// ---------------------------------------------------------------------------
__global__ void copy_zq_kernel(float* __restrict__ out) {
  size_t t = (size_t)blockIdx.x * 256 + threadIdx.x;
  float4 v = ((const float4*)out)[t];
  float* dst = out + OFF_ZQ + t * 4;
  ((float2*)dst)[0] = make_float2(v.x, v.y);
  ((float2*)dst)[1] = make_float2(v.z, v.w);
}

// ---------------------------------------------------------------------------
// K5: vq_loss (sum of 1024 wave partials) + perplexity
// ---------------------------------------------------------------------------
__global__ void finalize_kernel(const float* __restrict__ ema,
                                const double* __restrict__ partials,
                                float* __restrict__ out) {
  __shared__ double red[256];
  const int t = threadIdx.x;

  double cs = partials[t] + partials[t + 256] + partials[t + 512] + partials[t + 768];
  red[t] = cs;
  __syncthreads();
  for (int off = 128; off > 0; off >>= 1) {
    if (t < off) red[t] += red[t + off];
    __syncthreads();
  }
  double commit = red[0];
  __syncthreads();

  double s = 0.0;
  for (int i = t; i < K_CODES; i += 256) s += (double)(ema[i] + 1e-10f);
  red[t] = s;
  __syncthreads();
  for (int off = 128; off > 0; off >>= 1) {
    if (t < off) red[t] += red[t + off];
    __syncthreads();
  }
  double S = red[0];
  __syncthreads();

  double h = 0.0;
  for (int i = t; i < K_CODES; i += 256) {
    float p = (float)((ema[i] + 1e-10f) / (float)S);
    h += (double)(p * logf(p));
  }
  red[t] = h;
  __syncthreads();
  for (int off = 128; off > 0; off >>= 1) {
    if (t < off) red[t] += red[t + off];
    __syncthreads();
  }

  if (t == 0) {
    out[OFF_SCAL]     = 0.25f * (float)(commit / (double)((size_t)M_ROWS * (size_t)D_DIM));
    out[OFF_SCAL + 1] = expf((float)(-red[0]));
  }
}

extern "C" void kernel_launch(void* const* d_in, const int* in_sizes, int n_in,
                              void* d_out, int out_size, void* d_ws, size_t ws_size,
                              hipStream_t stream) {
  (void)in_sizes; (void)n_in; (void)out_size;
  const float* z_e = (const float*)d_in[0];
  const float* cb  = (const float*)d_in[1];
  const float* ema = (const float*)d_in[2];
  float* out = (float*)d_out;

  double* partials = (double*)d_ws;                         // 1024 doubles, 8 KB
  float* e2        = (float*)((char*)d_ws + 8192);          // 16 KB
  char*  img       = (char*)d_out + IMG_OFF;                // 1 MB scratch in z_q_st region
  float* e2b       = (float*)((char*)d_out + E2B_OFF);      // 16 KB scratch

  const size_t cand_bytes = (size_t)M_ROWS * 32 * 8;        // 16 MB
  const int use_ws = (ws_size >= 32768 + cand_bytes) ? 1 : 0;
  u64* cand64 = use_ws
      ? (u64*)((char*)d_ws + 32768)
      : (u64*)((char*)d_out + CANDB_OFF);                   // z_q region, needs copy pass

  (void)hipMemsetAsync(d_ws, 0, 8192, stream);
  e2_kernel<<<K_CODES / 256, 256, 0, stream>>>(cb, e2, e2b);
  img_kernel<<<(K_CODES * D_DIM / 4) / 256, 256, 0, stream>>>(cb, img);
  vq_mfma_kernel<<<(M_ROWS / 512) * NSPLIT, 512, 0, stream>>>(z_e, img, e2b, cand64);
  pick_kernel<<<M_ROWS / 128, 128, 0, stream>>>(z_e, cb, e2, cand64, out, partials, use_ws);
  if (!use_ws)
    copy_zq_kernel<<<(M_ROWS * D_DIM / 4) / 256, 256, 0, stream>>>(out);
  finalize_kernel<<<1, 256, 0, stream>>>(ema, partials, out);
}

// Round 9
// 253.388 us; speedup vs baseline: 3.8852x; 3.8852x over previous
//
#include <hip/hip_runtime.h>
#include <cmath>

#define M_ROWS  65536
#define D_DIM   64
#define K_CODES 4096

// d_out float offsets (z_q_st | indices | vq_loss | perplexity | z_q)
#define OFF_IDX  4194304
#define OFF_SCAL 4259840
#define OFF_ZQ   4259842

// scratch regions inside d_out (consumed before their region is written)
#define IMG_OFF   (4u << 20)                 // codebook image, 1 MB (in z_q_st region)
#define E2B_OFF   (IMG_OFF + 1048576u)       // e2+32 array, 16 KB
#define CANDB_OFF 17039368u                  // == OFF_ZQ*4 : fallback cand64 region (16 MB, overwritten by copy_zq)

// codebook chunk image: 128 codes, bf16 hi/lo split, 128 B/row, XOR-swizzled granules
#define CH_LO    16384
#define CH_BYTES 32768
#define CH_QUADS 2048
#define NSPLIT   8
#define NCHB     4                            // chunks per block (512 codes)

typedef __attribute__((ext_vector_type(8))) short s16x8;
typedef __attribute__((ext_vector_type(4))) float f32x4;
typedef unsigned long long u64;

__device__ __forceinline__ unsigned short f2bf(float f) {   // RNE float->bf16 bits
  unsigned int u = __float_as_uint(f);
  return (unsigned short)((u + 0x7FFFu + ((u >> 16) & 1u)) >> 16);
}
__device__ __forceinline__ float bf2f(unsigned short h) {
  return __uint_as_float(((unsigned int)h) << 16);
}
__device__ __forceinline__ unsigned int umin_(unsigned int a, unsigned int b) {
  return a < b ? a : b;
}
// second-min update: with invariant b1 <= b2, new b2 = median(old b1, b2, key)
__device__ __forceinline__ unsigned int med3_u32(unsigned int a, unsigned int b, unsigned int c) {
  unsigned int d;
  asm("v_med3_u32 %0, %1, %2, %3" : "=v"(d) : "v"(a), "v"(b), "v"(c));
  return d;
}

// ---------------------------------------------------------------------------
// K1a: e2[k] exact (numpy 8-accumulator pairwise pattern, float4 loads)
// ---------------------------------------------------------------------------
__global__ void e2_kernel(const float* __restrict__ cb,
                          float* __restrict__ e2, float* __restrict__ e2b) {
  int k = blockIdx.x * 256 + threadIdx.x;
  if (k >= K_CODES) return;
  const float4* row = (const float4*)(cb + (size_t)k * D_DIM);
  float4 q[16];
#pragma unroll
  for (int i = 0; i < 16; ++i) q[i] = row[i];
  float s;
  {
#pragma clang fp contract(off)
    float r[8];
    {
      const float* f = (const float*)&q[0];
#pragma unroll
      for (int j = 0; j < 8; ++j) r[j] = f[j] * f[j];
    }
#pragma unroll
    for (int a = 1; a < 8; ++a) {
      const float* f = (const float*)&q[2 * a];
#pragma unroll
      for (int j = 0; j < 8; ++j) r[j] = r[j] + f[j] * f[j];
    }
    s = ((r[0] + r[1]) + (r[2] + r[3])) + ((r[4] + r[5]) + (r[6] + r[7]));
  }
  e2[k] = s;
  e2b[k] = s + 32.0f;
}

// ---------------------------------------------------------------------------
// K1b: bf16 hi/lo split image, fully coalesced; granule g at ((g+r)&7)
// ---------------------------------------------------------------------------
__global__ void img_kernel(const float* __restrict__ cb, char* __restrict__ img) {
  int t = blockIdx.x * 256 + threadIdx.x;   // 65536 threads, 4 elements each
  int k  = t >> 4;
  int d0 = (t & 15) * 4;
  float4 f = ((const float4*)cb)[t];
  ushort4 hi, lo;
  hi.x = f2bf(f.x); lo.x = f2bf(f.x - bf2f(hi.x));
  hi.y = f2bf(f.y); lo.y = f2bf(f.y - bf2f(hi.y));
  hi.z = f2bf(f.z); lo.z = f2bf(f.z - bf2f(hi.z));
  hi.w = f2bf(f.w); lo.w = f2bf(f.w - bf2f(hi.w));
  int c = k >> 7, r = k & 127;
  int g = d0 >> 3;
  int off = ((g + r) & 7) * 16 + (d0 & 7) * 2;
  char* base = img + (size_t)c * CH_BYTES + r * 128;
  *(ushort4*)(base + off) = hi;
  *(ushort4*)(base + CH_LO + off) = lo;
}

// ---------------------------------------------------------------------------
// K2: MFMA distance pass. 512 threads = 8 waves x 64 rows = 512 rows/block;
// K-split 8 -> grid 1024 = 4 blocks/CU. Round-6 body (64 VGPR, no spill):
// launch_bounds(512,4) -> VGPR cap 128 (achieved 64). val = (e2+32) - 2 z.e
// via 3 bf16-split products. key = (bits&~0xFF)|tile; top-2/elem min+med3;
// per-row top-4-of-32 -> cand64 COLUMN-MAJOR: cand64[slot*M + row].
// ---------------------------------------------------------------------------
__global__ __launch_bounds__(512, 4)
void vq_mfma_kernel(const float* __restrict__ z_e,
                    const char* __restrict__ img,
                    const float* __restrict__ e2b,
                    u64* __restrict__ cand64) {
  __shared__ union {
    uint4 q[CH_QUADS];
    char raw[CH_BYTES];
    unsigned int cand[256 * 33];     // 33792 B
  } sm;
  __shared__ float lds_e2[128];
  const int tid  = threadIdx.x;
  const int wave = tid >> 6, lane = tid & 63;
  const int quad = lane >> 4, c16 = lane & 15;
  const int rb   = blockIdx.x >> 3;           // row-group of 512
  const int sp   = blockIdx.x & 7;            // K-split id
  const int mb   = rb * 512 + wave * 64;

  // A-fragments: 4 row-tiles x (k-halves) x (hi/lo), A[m=lane&15][k=quad*8+j]
  s16x8 zh[4][2], zl[4][2];
#pragma unroll
  for (int mt = 0; mt < 4; ++mt) {
    int m = mb + mt * 16 + c16;
#pragma unroll
    for (int s = 0; s < 2; ++s) {
      const float* zp = z_e + (size_t)m * 64 + s * 32 + quad * 8;
      float4 fa = ((const float4*)zp)[0];
      float4 fb = ((const float4*)zp)[1];
      float v[8] = {fa.x, fa.y, fa.z, fa.w, fb.x, fb.y, fb.z, fb.w};
      union { s16x8 v8; unsigned short e[8]; } H, L;
#pragma unroll
      for (int j = 0; j < 8; ++j) {
        float f = -2.0f * v[j];
        unsigned short h = f2bf(f);
        H.e[j] = h;
        L.e[j] = f2bf(f - bf2f(h));
      }
      zh[mt][s] = H.v8;
      zl[mt][s] = L.v8;
    }
  }

  unsigned int b1[4][4], b2[4][4];
#pragma unroll
  for (int mt = 0; mt < 4; ++mt)
#pragma unroll
    for (int r = 0; r < 4; ++r) { b1[mt][r] = 0xFFFFFFFFu; b2[mt][r] = 0xFFFFFFFFu; }

  const int swz0 = ((quad + c16) & 7) * 16;       // t-invariant swizzle offsets
  const int swz1 = ((quad + 4 + c16) & 7) * 16;

  for (int c = 0; c < NCHB; ++c) {
    __syncthreads();
    {
      const uint4* src = (const uint4*)(img + (size_t)(sp * NCHB + c) * CH_BYTES);
#pragma unroll
      for (int i = 0; i < 4; ++i) sm.q[tid + i * 512] = src[tid + i * 512];
      if (tid < 128) lds_e2[tid] = e2b[sp * 512 + c * 128 + tid];
    }
    __syncthreads();

#pragma unroll 1
    for (int t = 0; t < 8; ++t) {
      const char* hb = sm.raw + (t * 16 + c16) * 128;
      s16x8 Bh0 = *(const s16x8*)(hb + swz0);
      s16x8 Bh1 = *(const s16x8*)(hb + swz1);
      s16x8 Bl0 = *(const s16x8*)(hb + CH_LO + swz0);
      s16x8 Bl1 = *(const s16x8*)(hb + CH_LO + swz1);
      float e2v = lds_e2[t * 16 + c16];
      unsigned int tid8 = (unsigned int)(sp * 32 + c * 8 + t);  // global 16-code tile id
      f32x4 cvec = {e2v, e2v, e2v, e2v};

#pragma unroll
      for (int mt = 0; mt < 4; ++mt) {
        f32x4 acc;
        acc = __builtin_amdgcn_mfma_f32_16x16x32_bf16(zh[mt][0], Bh0, cvec, 0, 0, 0);
        acc = __builtin_amdgcn_mfma_f32_16x16x32_bf16(zh[mt][1], Bh1, acc, 0, 0, 0);
        acc = __builtin_amdgcn_mfma_f32_16x16x32_bf16(zl[mt][0], Bh0, acc, 0, 0, 0);
        acc = __builtin_amdgcn_mfma_f32_16x16x32_bf16(zl[mt][1], Bh1, acc, 0, 0, 0);
        acc = __builtin_amdgcn_mfma_f32_16x16x32_bf16(zh[mt][0], Bl0, acc, 0, 0, 0);
        acc = __builtin_amdgcn_mfma_f32_16x16x32_bf16(zh[mt][1], Bl1, acc, 0, 0, 0);
#pragma unroll
        for (int r = 0; r < 4; ++r) {
          unsigned int key = (__float_as_uint(acc[r]) & 0xFFFFFF00u) | tid8;
          b2[mt][r] = med3_u32(b1[mt][r], b2[mt][r], key);
          b1[mt][r] = umin_(b1[mt][r], key);
        }
      }
    }
  }

  // final selection: two passes of 256 rows through the cand buffer
  for (int pass = 0; pass < 2; ++pass) {
    __syncthreads();
    if ((wave >> 2) == pass) {
      int wl = wave & 3;
#pragma unroll
      for (int mt = 0; mt < 4; ++mt)
#pragma unroll
        for (int r = 0; r < 4; ++r) {
          int lr = wl * 64 + mt * 16 + quad * 4 + r;   // C: col=lane&15, row=quad*4+reg
          sm.cand[lr * 33 + c16 * 2 + 0] = b1[mt][r];
          sm.cand[lr * 33 + c16 * 2 + 1] = b2[mt][r];
        }
    }
    __syncthreads();
    if (tid < 256) {
      unsigned int kk[4] = {0xFFFFFFFFu, 0xFFFFFFFFu, 0xFFFFFFFFu, 0xFFFFFFFFu};
      unsigned int vv[4] = {0, 0, 0, 0};
      for (int j = 0; j < 32; ++j) {
        unsigned int key = sm.cand[tid * 33 + j];
        if (key < kk[3]) {
          kk[3] = key;
          vv[3] = (key & 0xFFu) * 16 + (unsigned int)(j >> 1);  // k = tile*16 + col
          for (int p = 3; p > 0; --p)
            if (kk[p] < kk[p - 1]) {
              unsigned int a = kk[p]; kk[p] = kk[p - 1]; kk[p - 1] = a;
              unsigned int b = vv[p]; vv[p] = vv[p - 1]; vv[p - 1] = b;
            }
        }
      }
      int grow = rb * 512 + pass * 256 + tid;
#pragma unroll
      for (int i = 0; i < 4; ++i)
        cand64[(size_t)(sp * 4 + i) * M_ROWS + grow] = ((u64)kk[i] << 32) | (u64)vv[i];
    }
  }
}

// ---------------------------------------------------------------------------
// K3: tail. One thread per row. Coalesced column-major cand scan -> top-4.
// Gap gate: if 2nd quantized key >= best + 4 quanta, winner decided (approx
// error ~1e-5 << quantum 0.002) -> no exact check. Else serial exact check of
// 4 cands with the bit-exact numpy formula (first-min tie-break). Winner
// gather + outputs + per-wave loss partials.
// ---------------------------------------------------------------------------
__global__ __launch_bounds__(256)
void pick_kernel(const float* __restrict__ z_e, const float* __restrict__ cb,
                 const float* __restrict__ e2, const u64* __restrict__ cand64,
                 float* __restrict__ out, double* __restrict__ partials, int write_zq) {
  const int tid = threadIdx.x;
  const int r   = blockIdx.x * 256 + tid;

  // top-4 of 32 by u64 (key high; low bits k -> equal keys prefer smaller k)
  u64 t4[4] = {~0ull, ~0ull, ~0ull, ~0ull};
#pragma unroll 1
  for (int j = 0; j < 32; ++j) {
    u64 v = cand64[(size_t)j * M_ROWS + r];       // coalesced across lanes
    if (v < t4[3]) {
      t4[3] = v;
#pragma unroll
      for (int p = 3; p > 0; --p)
        if (t4[p] < t4[p - 1]) { u64 a = t4[p]; t4[p] = t4[p - 1]; t4[p - 1] = a; }
    }
  }

  // z row (needed for commit loss regardless)
  const float4* zr = (const float4*)(z_e + (size_t)r * 64);
  float4 z4[16];
#pragma unroll
  for (int i = 0; i < 16; ++i) z4[i] = zr[i];

  int bk;
  unsigned int key1 = (unsigned int)(t4[0] >> 32) & 0xFFFFFF00u;
  unsigned int key2 = (unsigned int)(t4[1] >> 32) & 0xFFFFFF00u;
  if (key2 - key1 >= 1024u) {
    bk = (int)(unsigned int)(t4[0] & 0xFFFFFFFFu);   // unambiguous winner
  } else {
    // exact re-check of the 4 candidates (bit-exact numpy formula)
    float z2;
    {
#pragma clang fp contract(off)
      float rr[8];
      {
        const float* f = (const float*)&z4[0];
#pragma unroll
        for (int j = 0; j < 8; ++j) rr[j] = f[j] * f[j];
      }
#pragma unroll
      for (int a = 1; a < 8; ++a) {
        const float* f = (const float*)&z4[2 * a];
#pragma unroll
        for (int j = 0; j < 8; ++j) rr[j] = rr[j] + f[j] * f[j];
      }
      z2 = ((rr[0] + rr[1]) + (rr[2] + rr[3])) + ((rr[4] + rr[5]) + (rr[6] + rr[7]));
    }
    float bd = INFINITY;
    bk = K_CODES;
#pragma unroll 1
    for (int i = 0; i < 4; ++i) {
      int k = (int)(unsigned int)(t4[i] & 0xFFFFFFFFu);
      const float4* ev = (const float4*)(cb + (size_t)k * 64);
      float4 a0 = make_float4(0.f, 0.f, 0.f, 0.f);
      float4 a1 = make_float4(0.f, 0.f, 0.f, 0.f);
      float4 a2 = make_float4(0.f, 0.f, 0.f, 0.f);
      float4 a3 = make_float4(0.f, 0.f, 0.f, 0.f);
#pragma unroll
      for (int q = 0; q < 4; ++q) {
        float4 e0 = ev[4 * q + 0], e1 = ev[4 * q + 1], e2v = ev[4 * q + 2], e3 = ev[4 * q + 3];
        a0.x = fmaf(z4[4 * q + 0].x, e0.x, a0.x); a0.y = fmaf(z4[4 * q + 0].y, e0.y, a0.y);
        a0.z = fmaf(z4[4 * q + 0].z, e0.z, a0.z); a0.w = fmaf(z4[4 * q + 0].w, e0.w, a0.w);
        a1.x = fmaf(z4[4 * q + 1].x, e1.x, a1.x); a1.y = fmaf(z4[4 * q + 1].y, e1.y, a1.y);
        a1.z = fmaf(z4[4 * q + 1].z, e1.z, a1.z); a1.w = fmaf(z4[4 * q + 1].w, e1.w, a1.w);
        a2.x = fmaf(z4[4 * q + 2].x, e2v.x, a2.x); a2.y = fmaf(z4[4 * q + 2].y, e2v.y, a2.y);
        a2.z = fmaf(z4[4 * q + 2].z, e2v.z, a2.z); a2.w = fmaf(z4[4 * q + 2].w, e2v.w, a2.w);
        a3.x = fmaf(z4[4 * q + 3].x, e3.x, a3.x); a3.y = fmaf(z4[4 * q + 3].y, e3.y, a3.y);
        a3.z = fmaf(z4[4 * q + 3].z, e3.z, a3.z); a3.w = fmaf(z4[4 * q + 3].w, e3.w, a3.w);
      }
      float d;
      {
#pragma clang fp contract(off)
        float sx = (a0.x + a1.x) + (a2.x + a3.x);
        float sy = (a0.y + a1.y) + (a2.y + a3.y);
        float sz = (a0.z + a1.z) + (a2.z + a3.z);
        float sw = (a0.w + a1.w) + (a2.w + a3.w);
        float dot = (sx + sy) + (sz + sw);
        float tt = z2 + e2[k];
        d = tt - 2.0f * dot;
      }
      if (d < bd || (d == bd && k < bk)) { bd = d; bk = k; }
    }
  }

  out[OFF_IDX + r] = (float)bk;

  // winner row: gather (L2-hot), write outputs, commit-loss partial
  const float4* qv = (const float4*)(cb + (size_t)bk * 64);
  float4* o0 = (float4*)(out + (size_t)r * 64);
  float* o1 = out + OFF_ZQ + (size_t)r * 64;     // 8B-aligned only
  double csum = 0.0;
#pragma unroll
  for (int i = 0; i < 16; ++i) {
    float4 q = qv[i];
    o0[i] = q;
    if (write_zq) {
      ((float2*)o1)[2 * i]     = make_float2(q.x, q.y);
      ((float2*)o1)[2 * i + 1] = make_float2(q.z, q.w);
    }
    float dx = z4[i].x - q.x; csum += (double)dx * (double)dx;
    float dy = z4[i].y - q.y; csum += (double)dy * (double)dy;
    float dz = z4[i].z - q.z; csum += (double)dz * (double)dz;
    float dw = z4[i].w - q.w; csum += (double)dw * (double)dw;
  }
#pragma unroll
  for (int off = 32; off > 0; off >>= 1) csum += __shfl_down(csum, off);
  if ((tid & 63) == 0) partials[blockIdx.x * 4 + (tid >> 6)] = csum;
}

// ---------------------------------------------------------------------------
// K4 (fallback only): z_q <- z_q_st; overwrites cand scratch in z_q region.
// ---------------------------------------------------------------------------
__global__ void copy_zq_kernel(float* __restrict__ out) {
  size_t t = (size_t)blockIdx.x * 256 + threadIdx.x;
  float4 v = ((const float4*)out)[t];
  float* dst = out + OFF_ZQ + t * 4;
  ((float2*)dst)[0] = make_float2(v.x, v.y);
  ((float2*)dst)[1] = make_float2(v.z, v.w);
}

// ---------------------------------------------------------------------------
// K5: vq_loss (sum of 1024 wave partials) + perplexity
// ---------------------------------------------------------------------------
__global__ void finalize_kernel(const float* __restrict__ ema,
                                const double* __restrict__ partials,
                                float* __restrict__ out) {
  __shared__ double red[256];
  const int t = threadIdx.x;

  double cs = partials[t] + partials[t + 256] + partials[t + 512] + partials[t + 768];
  red[t] = cs;
  __syncthreads();
  for (int off = 128; off > 0; off >>= 1) {
    if (t < off) red[t] += red[t + off];
    __syncthreads();
  }
  double commit = red[0];
  __syncthreads();

  double s = 0.0;
  for (int i = t; i < K_CODES; i += 256) s += (double)(ema[i] + 1e-10f);
  red[t] = s;
  __syncthreads();
  for (int off = 128; off > 0; off >>= 1) {
    if (t < off) red[t] += red[t + off];
    __syncthreads();
  }
  double S = red[0];
  __syncthreads();

  double h = 0.0;
  for (int i = t; i < K_CODES; i += 256) {
    float p = (float)((ema[i] + 1e-10f) / (float)S);
    h += (double)(p * logf(p));
  }
  red[t] = h;
  __syncthreads();
  for (int off = 128; off > 0; off >>= 1) {
    if (t < off) red[t] += red[t + off];
    __syncthreads();
  }

  if (t == 0) {
    out[OFF_SCAL]     = 0.25f * (float)(commit / (double)((size_t)M_ROWS * (size_t)D_DIM));
    out[OFF_SCAL + 1] = expf((float)(-red[0]));
  }
}

extern "C" void kernel_launch(void* const* d_in, const int* in_sizes, int n_in,
                              void* d_out, int out_size, void* d_ws, size_t ws_size,
                              hipStream_t stream) {
  (void)in_sizes; (void)n_in; (void)out_size;
  const float* z_e = (const float*)d_in[0];
  const float* cb  = (const float*)d_in[1];
  const float* ema = (const float*)d_in[2];
  float* out = (float*)d_out;

  double* partials = (double*)d_ws;                         // 1024 doubles, 8 KB
  float* e2        = (float*)((char*)d_ws + 8192);          // 16 KB
  char*  img       = (char*)d_out + IMG_OFF;                // 1 MB scratch in z_q_st region
  float* e2b       = (float*)((char*)d_out + E2B_OFF);      // 16 KB scratch

  const size_t cand_bytes = (size_t)M_ROWS * 32 * 8;        // 16 MB
  const int use_ws = (ws_size >= 32768 + cand_bytes) ? 1 : 0;
  u64* cand64 = use_ws
      ? (u64*)((char*)d_ws + 32768)
      : (u64*)((char*)d_out + CANDB_OFF);                   // z_q region, needs copy pass

  (void)hipMemsetAsync(d_ws, 0, 8192, stream);
  e2_kernel<<<K_CODES / 256, 256, 0, stream>>>(cb, e2, e2b);
  img_kernel<<<(K_CODES * D_DIM / 4) / 256, 256, 0, stream>>>(cb, img);
  vq_mfma_kernel<<<(M_ROWS / 512) * NSPLIT, 512, 0, stream>>>(z_e, img, e2b, cand64);
  pick_kernel<<<M_ROWS / 256, 256, 0, stream>>>(z_e, cb, e2, cand64, out, partials, use_ws);
  if (!use_ws)
    copy_zq_kernel<<<(M_ROWS * D_DIM / 4) / 256, 256, 0, stream>>>(out);
  finalize_kernel<<<1, 256, 0, stream>>>(ema, partials, out);
}